// Round 1
// baseline (1280.827 us; speedup 1.0000x reference)
//
#include <hip/hip_runtime.h>
#include <hip/hip_bf16.h>
#include <cstddef>

#define NNODES 100000
#define NEDGES 1600000
#define CIN 128
#define HID 256
#define ACT 20
#define NGRAPH (NNODES / ACT)

// ---------------- degree / norm ----------------

__global__ void deg_init_k(float* __restrict__ deg) {
    int i = blockIdx.x * 256 + threadIdx.x;
    if (i < NNODES) deg[i] = 1.0f;   // self-loop
}

__global__ void deg_acc_k(const int* __restrict__ ei, float* __restrict__ deg) {
    int e = blockIdx.x * 256 + threadIdx.x;
    if (e < NEDGES) atomicAdd(&deg[ei[NEDGES + e]], 1.0f);
}

__global__ void dinv_k(const float* __restrict__ deg, float* __restrict__ dinv) {
    int i = blockIdx.x * 256 + threadIdx.x;
    if (i < NNODES) dinv[i] = rsqrtf(deg[i]);
}

// ---------------- fp32 register-tiled GEMM ----------------
// C[M,N] = op_epilogue( op_A(A)[M,K] @ B[K,N] )
// MODE 0: A = x direct; B = conv_w row-major [k][n]; epilogue writes
//         C0 = xw and C1 = xw * dinv[row]^2 (self-loop init of aggregation).
// MODE 1: A = relu(acc + abias) + Ares (residual); B = W[n][k] (torch layout);
//         epilogue C0 = relu(C + cbias).
// MODE 2: A direct; B = W[n][k]; epilogue C0 = relu(C + cbias).

template <int MODE>
__global__ __launch_bounds__(256) void gemm_k(
    const float* __restrict__ A, const float* __restrict__ Ares,
    const float* __restrict__ abias, const float* __restrict__ B,
    const float* __restrict__ cbias, const float* __restrict__ dinv,
    float* __restrict__ C0, float* __restrict__ C1,
    int M, int K, int ldb, int ldc)
{
    __shared__ float As[16][128];
    __shared__ float Bs[16][128];
    const int tid = threadIdx.x;
    const int bm = blockIdx.x * 128;
    const int bn = blockIdx.y * 128;
    const int tx = tid & 15;
    const int ty = tid >> 4;

    float acc[8][8];
#pragma unroll
    for (int i = 0; i < 8; ++i)
#pragma unroll
        for (int j = 0; j < 8; ++j) acc[i][j] = 0.f;

    const int ktiles = K >> 4;
    for (int kt = 0; kt < ktiles; ++kt) {
        const int k0 = kt << 4;
        // ---- stage A tile (transposed: As[k][m]) ----
#pragma unroll
        for (int t = 0; t < 2; ++t) {
            int id = tid + t * 256;        // 0..511 float4 slots
            int row = id >> 2;             // 0..127
            int kk = (id & 3) << 2;        // 0,4,8,12
            int grow = bm + row;
            float4 av = make_float4(0.f, 0.f, 0.f, 0.f);
            if (grow < M) {
                av = *reinterpret_cast<const float4*>(A + (size_t)grow * K + k0 + kk);
                if (MODE == 1) {
                    float4 xv = *reinterpret_cast<const float4*>(Ares + (size_t)grow * K + k0 + kk);
                    float4 bb = *reinterpret_cast<const float4*>(abias + k0 + kk);
                    av.x = fmaxf(av.x + bb.x, 0.f) + xv.x;
                    av.y = fmaxf(av.y + bb.y, 0.f) + xv.y;
                    av.z = fmaxf(av.z + bb.z, 0.f) + xv.z;
                    av.w = fmaxf(av.w + bb.w, 0.f) + xv.w;
                }
            }
            As[kk + 0][row] = av.x;
            As[kk + 1][row] = av.y;
            As[kk + 2][row] = av.z;
            As[kk + 3][row] = av.w;
        }
        // ---- stage B tile (Bs[k][n]) ----
        if (MODE == 0) {
#pragma unroll
            for (int t = 0; t < 2; ++t) {
                int id = tid + t * 256;
                int kr = id >> 5;            // 0..15
                int nc = (id & 31) << 2;     // 0..124
                float4 bv = *reinterpret_cast<const float4*>(B + (size_t)(k0 + kr) * ldb + bn + nc);
                *reinterpret_cast<float4*>(&Bs[kr][nc]) = bv;
            }
        } else {
#pragma unroll
            for (int t = 0; t < 2; ++t) {
                int id = tid + t * 256;
                int n = id >> 2;             // 0..127
                int kk = (id & 3) << 2;      // 0,4,8,12
                float4 bv = *reinterpret_cast<const float4*>(B + (size_t)(bn + n) * ldb + k0 + kk);
                Bs[kk + 0][n] = bv.x;
                Bs[kk + 1][n] = bv.y;
                Bs[kk + 2][n] = bv.z;
                Bs[kk + 3][n] = bv.w;
            }
        }
        __syncthreads();
        // ---- 8x8 microtile FMA ----
#pragma unroll
        for (int kk = 0; kk < 16; ++kk) {
            float a[8], b[8];
            *reinterpret_cast<float4*>(&a[0]) = *reinterpret_cast<const float4*>(&As[kk][ty * 8]);
            *reinterpret_cast<float4*>(&a[4]) = *reinterpret_cast<const float4*>(&As[kk][ty * 8 + 4]);
            *reinterpret_cast<float4*>(&b[0]) = *reinterpret_cast<const float4*>(&Bs[kk][tx * 8]);
            *reinterpret_cast<float4*>(&b[4]) = *reinterpret_cast<const float4*>(&Bs[kk][tx * 8 + 4]);
#pragma unroll
            for (int i = 0; i < 8; ++i)
#pragma unroll
                for (int j = 0; j < 8; ++j)
                    acc[i][j] = fmaf(a[i], b[j], acc[i][j]);
        }
        __syncthreads();
    }

    // ---- epilogue ----
    const int col0 = bn + tx * 8;
#pragma unroll
    for (int i = 0; i < 8; ++i) {
        int row = bm + ty * 8 + i;
        if (row >= M) continue;
        if (MODE == 0) {
            float dv = dinv[row];
            float dv2 = dv * dv;
            float4 v0 = make_float4(acc[i][0], acc[i][1], acc[i][2], acc[i][3]);
            float4 v1 = make_float4(acc[i][4], acc[i][5], acc[i][6], acc[i][7]);
            *reinterpret_cast<float4*>(C0 + (size_t)row * ldc + col0) = v0;
            *reinterpret_cast<float4*>(C0 + (size_t)row * ldc + col0 + 4) = v1;
            float4 w0 = make_float4(v0.x * dv2, v0.y * dv2, v0.z * dv2, v0.w * dv2);
            float4 w1 = make_float4(v1.x * dv2, v1.y * dv2, v1.z * dv2, v1.w * dv2);
            *reinterpret_cast<float4*>(C1 + (size_t)row * ldc + col0) = w0;
            *reinterpret_cast<float4*>(C1 + (size_t)row * ldc + col0 + 4) = w1;
        } else {
            float4 b0 = *reinterpret_cast<const float4*>(cbias + col0);
            float4 b1 = *reinterpret_cast<const float4*>(cbias + col0 + 4);
            float4 v0 = make_float4(fmaxf(acc[i][0] + b0.x, 0.f), fmaxf(acc[i][1] + b0.y, 0.f),
                                    fmaxf(acc[i][2] + b0.z, 0.f), fmaxf(acc[i][3] + b0.w, 0.f));
            float4 v1 = make_float4(fmaxf(acc[i][4] + b1.x, 0.f), fmaxf(acc[i][5] + b1.y, 0.f),
                                    fmaxf(acc[i][6] + b1.z, 0.f), fmaxf(acc[i][7] + b1.w, 0.f));
            *reinterpret_cast<float4*>(C0 + (size_t)row * ldc + col0) = v0;
            *reinterpret_cast<float4*>(C0 + (size_t)row * ldc + col0 + 4) = v1;
        }
    }
}

// ---------------- edge scatter (atomic) ----------------
// acc[dst][c] += xw[src][c] * dinv[src]*dinv[dst]; 2 edges per 256-thread block

__global__ __launch_bounds__(256) void scatter_k(
    const int* __restrict__ ei, const float* __restrict__ xw,
    const float* __restrict__ dinv, float* __restrict__ acc)
{
    int e = blockIdx.x * 2 + (threadIdx.x >> 7);
    int c = threadIdx.x & 127;
    if (e < NEDGES) {
        int s = ei[e];
        int d = ei[NEDGES + e];
        float nrm = dinv[s] * dinv[d];
        atomicAdd(&acc[(size_t)d * CIN + c], xw[(size_t)s * CIN + c] * nrm);
    }
}

// ---------------- per-graph sum + lin3 ----------------

__global__ __launch_bounds__(256) void final_k(
    const float* __restrict__ h2, const float* __restrict__ w3,
    const float* __restrict__ b3, float* __restrict__ out)
{
    int b = blockIdx.x;
    int n = threadIdx.x;
    const float* p = h2 + (size_t)b * ACT * HID + n;
    float s = 0.f;
#pragma unroll
    for (int i = 0; i < ACT; ++i) s += p[(size_t)i * HID];
    float v = s * w3[n];
    __shared__ float red[4];
#pragma unroll
    for (int off = 32; off > 0; off >>= 1) v += __shfl_down(v, off, 64);
    if ((n & 63) == 0) red[n >> 6] = v;
    __syncthreads();
    if (n == 0) out[b] = red[0] + red[1] + red[2] + red[3] + b3[0];
}

// ---------------- launch ----------------

extern "C" void kernel_launch(void* const* d_in, const int* in_sizes, int n_in,
                              void* d_out, int out_size, void* d_ws, size_t ws_size,
                              hipStream_t stream)
{
    const float* x      = (const float*)d_in[0];
    const int*   ei     = (const int*)  d_in[1];
    const float* conv_w = (const float*)d_in[2];
    const float* conv_b = (const float*)d_in[3];
    const float* lin1_w = (const float*)d_in[4];
    const float* lin1_b = (const float*)d_in[5];
    const float* lin2_w = (const float*)d_in[6];
    const float* lin2_b = (const float*)d_in[7];
    const float* lin3_w = (const float*)d_in[8];
    const float* lin3_b = (const float*)d_in[9];
    float* out = (float*)d_out;

    // workspace layout (floats): deg[N] | dinv[N] | xw[N*128] | acc[N*128] | h1[N*256]
    // h2[N*256] reuses xw+acc (both dead by then). Total 205.6 MB.
    float* ws   = (float*)d_ws;
    float* deg  = ws;
    float* dinv = ws + NNODES;
    float* xw   = ws + 2 * NNODES;
    float* acc  = xw + (size_t)NNODES * CIN;
    float* h1   = acc + (size_t)NNODES * CIN;
    float* h2   = xw;

    deg_init_k<<<(NNODES + 255) / 256, 256, 0, stream>>>(deg);
    deg_acc_k<<<(NEDGES + 255) / 256, 256, 0, stream>>>(ei, deg);
    dinv_k<<<(NNODES + 255) / 256, 256, 0, stream>>>(deg, dinv);

    dim3 g1((NNODES + 127) / 128, 1);
    gemm_k<0><<<g1, 256, 0, stream>>>(x, nullptr, nullptr, conv_w, nullptr, dinv,
                                      xw, acc, NNODES, CIN, CIN, CIN);

    scatter_k<<<NEDGES / 2, 256, 0, stream>>>(ei, xw, dinv, acc);

    dim3 g2((NNODES + 127) / 128, HID / 128);
    gemm_k<1><<<g2, 256, 0, stream>>>(acc, x, conv_b, lin1_w, lin1_b, nullptr,
                                      h1, nullptr, NNODES, CIN, CIN, HID);

    gemm_k<2><<<g2, 256, 0, stream>>>(h1, nullptr, nullptr, lin2_w, lin2_b, nullptr,
                                      h2, nullptr, NNODES, HID, HID, HID);

    final_k<<<NGRAPH, 256, 0, stream>>>(h2, lin3_w, lin3_b, out);
}

// Round 2
// 842.346 us; speedup vs baseline: 1.5205x; 1.5205x over previous
//
#include <hip/hip_runtime.h>
#include <hip/hip_bf16.h>
#include <cstddef>

#define NNODES 100000
#define NEDGES 1600000
#define CIN 128
#define HID 256
#define ACT 20
#define NGRAPH (NNODES / ACT)
#define NBLK ((NNODES + 255) / 256)   // 391 scan blocks

// ---------------- CSR build ----------------

__global__ void zero_int_k(int* __restrict__ p, int n) {
    int i = blockIdx.x * 256 + threadIdx.x;
    if (i < n) p[i] = 0;
}

__global__ void count_k(const int* __restrict__ ei, int* __restrict__ cnt) {
    int e = blockIdx.x * 256 + threadIdx.x;
    if (e < NEDGES) atomicAdd(&cnt[ei[NEDGES + e]], 1);
}

__global__ void dinv_k(const int* __restrict__ cnt, float* __restrict__ dinv) {
    int i = blockIdx.x * 256 + threadIdx.x;
    if (i < NNODES) dinv[i] = rsqrtf(1.0f + (float)cnt[i]);
}

// exclusive scan of cnt -> rowptr, per-block totals -> bsum
__global__ __launch_bounds__(256) void scan1_k(const int* __restrict__ cnt,
                                               int* __restrict__ rowptr,
                                               int* __restrict__ bsum) {
    int i = blockIdx.x * 256 + threadIdx.x;
    int lane = threadIdx.x & 63, wid = threadIdx.x >> 6;
    int v = (i < NNODES) ? cnt[i] : 0;
    int inc = v;
#pragma unroll
    for (int off = 1; off < 64; off <<= 1) {
        int t = __shfl_up(inc, off, 64);
        if (lane >= off) inc += t;
    }
    __shared__ int wsum[4];
    if (lane == 63) wsum[wid] = inc;
    __syncthreads();
    int woff = 0;
#pragma unroll
    for (int w = 0; w < 4; ++w) woff += (w < wid) ? wsum[w] : 0;
    int incl = inc + woff;
    if (i < NNODES) rowptr[i] = incl - v;
    if (threadIdx.x == 255) bsum[blockIdx.x] = incl;
}

// single-block exclusive scan of bsum[NBLK] in place
__global__ __launch_bounds__(512) void scan2_k(int* __restrict__ bsum) {
    int i = threadIdx.x;
    int lane = i & 63, wid = i >> 6;
    int v = (i < NBLK) ? bsum[i] : 0;
    int inc = v;
#pragma unroll
    for (int off = 1; off < 64; off <<= 1) {
        int t = __shfl_up(inc, off, 64);
        if (lane >= off) inc += t;
    }
    __shared__ int wsum[8];
    if (lane == 63) wsum[wid] = inc;
    __syncthreads();
    int woff = 0;
#pragma unroll
    for (int w = 0; w < 8; ++w) woff += (w < wid) ? wsum[w] : 0;
    if (i < NBLK) bsum[i] = inc + woff - v;   // exclusive
}

__global__ void scan3_k(int* __restrict__ rowptr, const int* __restrict__ bsum) {
    int i = blockIdx.x * 256 + threadIdx.x;
    if (i < NNODES) rowptr[i] += bsum[blockIdx.x];
}

// fill: destructive — after this, rowptr[d] = end(d); start(d) = d ? rowptr[d-1] : 0
__global__ void fill_k(const int* __restrict__ ei, int* __restrict__ rowptr,
                       int* __restrict__ csr) {
    int e = blockIdx.x * 256 + threadIdx.x;
    if (e < NEDGES) {
        int s = ei[e];
        int d = ei[NEDGES + e];
        int p = atomicAdd(&rowptr[d], 1);
        csr[p] = s;
    }
}

// ---------------- gather (no atomics) ----------------
// agg[d][c] = dinv[d] * ( xws[d][c] + sum_{e in(d)} xws[src_e][c] )

__global__ __launch_bounds__(256) void gather_k(
    const int* __restrict__ rowptr, const int* __restrict__ csr,
    const float* __restrict__ xws, const float* __restrict__ dinv,
    float* __restrict__ agg)
{
    int node = blockIdx.x * 2 + (threadIdx.x >> 7);
    int c = threadIdx.x & 127;
    if (node >= NNODES) return;
    int start = (node == 0) ? 0 : rowptr[node - 1];
    int end = rowptr[node];
    float s = xws[(size_t)node * CIN + c];
    int p = start;
    while (p < end) {
        int n = end - p;
        if (n > 8) n = 8;
        int idx[8];
#pragma unroll
        for (int j = 0; j < 8; ++j)
            if (j < n) idx[j] = csr[p + j];
#pragma unroll
        for (int j = 0; j < 8; ++j)
            if (j < n) s += xws[(size_t)idx[j] * CIN + c];
        p += n;
    }
    agg[(size_t)node * CIN + c] = s * dinv[node];
}

// ---------------- fp32 register-tiled GEMM ----------------
// MODE 0: C0 = (A @ B_rowmajor) * dinv[row]        (writes pre-scaled xws)
// MODE 1: A' = relu(A + abias) + Ares; C0 = relu(A' @ B^T + cbias)
// MODE 2: C0 = relu(A @ B^T + cbias)

template <int MODE>
__global__ __launch_bounds__(256) void gemm_k(
    const float* __restrict__ A, const float* __restrict__ Ares,
    const float* __restrict__ abias, const float* __restrict__ B,
    const float* __restrict__ cbias, const float* __restrict__ dinv,
    float* __restrict__ C0,
    int M, int K, int ldb, int ldc)
{
    __shared__ float As[16][128];
    __shared__ float Bs[16][128];
    const int tid = threadIdx.x;
    const int bm = blockIdx.x * 128;
    const int bn = blockIdx.y * 128;
    const int tx = tid & 15;
    const int ty = tid >> 4;

    float acc[8][8];
#pragma unroll
    for (int i = 0; i < 8; ++i)
#pragma unroll
        for (int j = 0; j < 8; ++j) acc[i][j] = 0.f;

    const int ktiles = K >> 4;
    for (int kt = 0; kt < ktiles; ++kt) {
        const int k0 = kt << 4;
#pragma unroll
        for (int t = 0; t < 2; ++t) {
            int id = tid + t * 256;
            int row = id >> 2;
            int kk = (id & 3) << 2;
            int grow = bm + row;
            float4 av = make_float4(0.f, 0.f, 0.f, 0.f);
            if (grow < M) {
                av = *reinterpret_cast<const float4*>(A + (size_t)grow * K + k0 + kk);
                if (MODE == 1) {
                    float4 xv = *reinterpret_cast<const float4*>(Ares + (size_t)grow * K + k0 + kk);
                    float4 bb = *reinterpret_cast<const float4*>(abias + k0 + kk);
                    av.x = fmaxf(av.x + bb.x, 0.f) + xv.x;
                    av.y = fmaxf(av.y + bb.y, 0.f) + xv.y;
                    av.z = fmaxf(av.z + bb.z, 0.f) + xv.z;
                    av.w = fmaxf(av.w + bb.w, 0.f) + xv.w;
                }
            }
            As[kk + 0][row] = av.x;
            As[kk + 1][row] = av.y;
            As[kk + 2][row] = av.z;
            As[kk + 3][row] = av.w;
        }
        if (MODE == 0) {
#pragma unroll
            for (int t = 0; t < 2; ++t) {
                int id = tid + t * 256;
                int kr = id >> 5;
                int nc = (id & 31) << 2;
                float4 bv = *reinterpret_cast<const float4*>(B + (size_t)(k0 + kr) * ldb + bn + nc);
                *reinterpret_cast<float4*>(&Bs[kr][nc]) = bv;
            }
        } else {
#pragma unroll
            for (int t = 0; t < 2; ++t) {
                int id = tid + t * 256;
                int n = id >> 2;
                int kk = (id & 3) << 2;
                float4 bv = *reinterpret_cast<const float4*>(B + (size_t)(bn + n) * ldb + k0 + kk);
                Bs[kk + 0][n] = bv.x;
                Bs[kk + 1][n] = bv.y;
                Bs[kk + 2][n] = bv.z;
                Bs[kk + 3][n] = bv.w;
            }
        }
        __syncthreads();
#pragma unroll
        for (int kk = 0; kk < 16; ++kk) {
            float a[8], b[8];
            *reinterpret_cast<float4*>(&a[0]) = *reinterpret_cast<const float4*>(&As[kk][ty * 8]);
            *reinterpret_cast<float4*>(&a[4]) = *reinterpret_cast<const float4*>(&As[kk][ty * 8 + 4]);
            *reinterpret_cast<float4*>(&b[0]) = *reinterpret_cast<const float4*>(&Bs[kk][tx * 8]);
            *reinterpret_cast<float4*>(&b[4]) = *reinterpret_cast<const float4*>(&Bs[kk][tx * 8 + 4]);
#pragma unroll
            for (int i = 0; i < 8; ++i)
#pragma unroll
                for (int j = 0; j < 8; ++j)
                    acc[i][j] = fmaf(a[i], b[j], acc[i][j]);
        }
        __syncthreads();
    }

    const int col0 = bn + tx * 8;
#pragma unroll
    for (int i = 0; i < 8; ++i) {
        int row = bm + ty * 8 + i;
        if (row >= M) continue;
        if (MODE == 0) {
            float dv = dinv[row];
            float4 v0 = make_float4(acc[i][0] * dv, acc[i][1] * dv, acc[i][2] * dv, acc[i][3] * dv);
            float4 v1 = make_float4(acc[i][4] * dv, acc[i][5] * dv, acc[i][6] * dv, acc[i][7] * dv);
            *reinterpret_cast<float4*>(C0 + (size_t)row * ldc + col0) = v0;
            *reinterpret_cast<float4*>(C0 + (size_t)row * ldc + col0 + 4) = v1;
        } else {
            float4 b0 = *reinterpret_cast<const float4*>(cbias + col0);
            float4 b1 = *reinterpret_cast<const float4*>(cbias + col0 + 4);
            float4 v0 = make_float4(fmaxf(acc[i][0] + b0.x, 0.f), fmaxf(acc[i][1] + b0.y, 0.f),
                                    fmaxf(acc[i][2] + b0.z, 0.f), fmaxf(acc[i][3] + b0.w, 0.f));
            float4 v1 = make_float4(fmaxf(acc[i][4] + b1.x, 0.f), fmaxf(acc[i][5] + b1.y, 0.f),
                                    fmaxf(acc[i][6] + b1.z, 0.f), fmaxf(acc[i][7] + b1.w, 0.f));
            *reinterpret_cast<float4*>(C0 + (size_t)row * ldc + col0) = v0;
            *reinterpret_cast<float4*>(C0 + (size_t)row * ldc + col0 + 4) = v1;
        }
    }
}

// ---------------- per-graph sum + lin3 ----------------

__global__ __launch_bounds__(256) void final_k(
    const float* __restrict__ h2, const float* __restrict__ w3,
    const float* __restrict__ b3, float* __restrict__ out)
{
    int b = blockIdx.x;
    int n = threadIdx.x;
    const float* p = h2 + (size_t)b * ACT * HID + n;
    float s = 0.f;
#pragma unroll
    for (int i = 0; i < ACT; ++i) s += p[(size_t)i * HID];
    float v = s * w3[n];
    __shared__ float red[4];
#pragma unroll
    for (int off = 32; off > 0; off >>= 1) v += __shfl_down(v, off, 64);
    if ((n & 63) == 0) red[n >> 6] = v;
    __syncthreads();
    if (n == 0) out[b] = red[0] + red[1] + red[2] + red[3] + b3[0];
}

// ---------------- launch ----------------

extern "C" void kernel_launch(void* const* d_in, const int* in_sizes, int n_in,
                              void* d_out, int out_size, void* d_ws, size_t ws_size,
                              hipStream_t stream)
{
    const float* x      = (const float*)d_in[0];
    const int*   ei     = (const int*)  d_in[1];
    const float* conv_w = (const float*)d_in[2];
    const float* conv_b = (const float*)d_in[3];
    const float* lin1_w = (const float*)d_in[4];
    const float* lin1_b = (const float*)d_in[5];
    const float* lin2_w = (const float*)d_in[6];
    const float* lin2_b = (const float*)d_in[7];
    const float* lin3_w = (const float*)d_in[8];
    const float* lin3_b = (const float*)d_in[9];
    float* out = (float*)d_out;

    // float workspace: xws[N*128] | agg[N*128] | h1[N*256]; h2 reuses xws+agg.
    // CSR int scratch + dinv alias the h1 region (dead until gemm1, by which
    // time csr/rowptr/count are dead; dinv stays live only through gather).
    float* ws  = (float*)d_ws;
    float* xws = ws;                                  // 12.8M floats
    float* agg = xws + (size_t)NNODES * CIN;          // 12.8M floats
    float* h1  = agg + (size_t)NNODES * CIN;          // 25.6M floats
    float* h2  = ws;                                  // reuse xws+agg (102.4 MB)

    int* cnt    = (int*)h1;
    int* rowptr = cnt + NNODES;
    int* csr    = rowptr + NNODES;
    int* bsum   = csr + NEDGES;
    float* dinv = (float*)(bsum + 512);

    zero_int_k<<<NBLK, 256, 0, stream>>>(cnt, NNODES);
    count_k<<<(NEDGES + 255) / 256, 256, 0, stream>>>(ei, cnt);
    dinv_k<<<NBLK, 256, 0, stream>>>(cnt, dinv);
    scan1_k<<<NBLK, 256, 0, stream>>>(cnt, rowptr, bsum);
    scan2_k<<<1, 512, 0, stream>>>(bsum);
    scan3_k<<<NBLK, 256, 0, stream>>>(rowptr, bsum);
    fill_k<<<(NEDGES + 255) / 256, 256, 0, stream>>>(ei, rowptr, csr);

    dim3 g1((NNODES + 127) / 128, 1);
    gemm_k<0><<<g1, 256, 0, stream>>>(x, nullptr, nullptr, conv_w, nullptr, dinv,
                                      xws, NNODES, CIN, CIN, CIN);

    gather_k<<<NNODES / 2, 256, 0, stream>>>(rowptr, csr, xws, dinv, agg);

    dim3 g2((NNODES + 127) / 128, HID / 128);
    gemm_k<1><<<g2, 256, 0, stream>>>(agg, x, conv_b, lin1_w, lin1_b, nullptr,
                                      h1, NNODES, CIN, CIN, HID);

    gemm_k<2><<<g2, 256, 0, stream>>>(h1, nullptr, nullptr, lin2_w, lin2_b, nullptr,
                                      h2, NNODES, HID, HID, HID);

    final_k<<<NGRAPH, 256, 0, stream>>>(h2, lin3_w, lin3_b, out);
}

// Round 3
// 605.892 us; speedup vs baseline: 2.1140x; 1.3903x over previous
//
#include <hip/hip_runtime.h>
#include <hip/hip_bf16.h>
#include <cstddef>

#define NNODES 100000
#define NEDGES 1600000
#define CIN 128
#define HID 256
#define ACT 20
#define NGRAPH (NNODES / ACT)
#define NBLK ((NNODES + 255) / 256)

typedef __attribute__((ext_vector_type(8))) short short8;
typedef __attribute__((ext_vector_type(4))) float f32x4;

__device__ __forceinline__ unsigned short f2b(float f) {
    unsigned u = __float_as_uint(f);
    u += 0x7FFF + ((u >> 16) & 1);          // round-to-nearest-even
    return (unsigned short)(u >> 16);
}
__device__ __forceinline__ float b2f(unsigned short h) {
    return __uint_as_float(((unsigned)h) << 16);
}

// ---------------- CSR build ----------------

__global__ void zero_int_k(int* __restrict__ p, int n) {
    int i = blockIdx.x * 256 + threadIdx.x;
    if (i < n) p[i] = 0;
}

__global__ void count_k(const int* __restrict__ ei, int* __restrict__ cnt) {
    int e = blockIdx.x * 256 + threadIdx.x;
    if (e < NEDGES) atomicAdd(&cnt[ei[NEDGES + e]], 1);
}

__global__ void dinv_k(const int* __restrict__ cnt, float* __restrict__ dinv) {
    int i = blockIdx.x * 256 + threadIdx.x;
    if (i < NNODES) dinv[i] = rsqrtf(1.0f + (float)cnt[i]);
}

__global__ __launch_bounds__(256) void scan1_k(const int* __restrict__ cnt,
                                               int* __restrict__ rowptr,
                                               int* __restrict__ bsum) {
    int i = blockIdx.x * 256 + threadIdx.x;
    int lane = threadIdx.x & 63, wid = threadIdx.x >> 6;
    int v = (i < NNODES) ? cnt[i] : 0;
    int inc = v;
#pragma unroll
    for (int off = 1; off < 64; off <<= 1) {
        int t = __shfl_up(inc, off, 64);
        if (lane >= off) inc += t;
    }
    __shared__ int wsum[4];
    if (lane == 63) wsum[wid] = inc;
    __syncthreads();
    int woff = 0;
#pragma unroll
    for (int w = 0; w < 4; ++w) woff += (w < wid) ? wsum[w] : 0;
    int incl = inc + woff;
    if (i < NNODES) rowptr[i] = incl - v;
    if (threadIdx.x == 255) bsum[blockIdx.x] = incl;
}

__global__ __launch_bounds__(512) void scan2_k(int* __restrict__ bsum) {
    int i = threadIdx.x;
    int lane = i & 63, wid = i >> 6;
    int v = (i < NBLK) ? bsum[i] : 0;
    int inc = v;
#pragma unroll
    for (int off = 1; off < 64; off <<= 1) {
        int t = __shfl_up(inc, off, 64);
        if (lane >= off) inc += t;
    }
    __shared__ int wsum[8];
    if (lane == 63) wsum[wid] = inc;
    __syncthreads();
    int woff = 0;
#pragma unroll
    for (int w = 0; w < 8; ++w) woff += (w < wid) ? wsum[w] : 0;
    if (i < NBLK) bsum[i] = inc + woff - v;
}

__global__ void scan3_k(int* __restrict__ rowptr, const int* __restrict__ bsum) {
    int i = blockIdx.x * 256 + threadIdx.x;
    if (i < NNODES) rowptr[i] += bsum[blockIdx.x];
}

__global__ void fill_k(const int* __restrict__ ei, int* __restrict__ rowptr,
                       int* __restrict__ csr) {
    int e = blockIdx.x * 256 + threadIdx.x;
    if (e < NEDGES) {
        int s = ei[e];
        int d = ei[NEDGES + e];
        int p = atomicAdd(&rowptr[d], 1);
        csr[p] = s;
    }
}

// ---------------- fp32 -> bf16 conversions ----------------

__global__ void cvt_bf16_k(const float* __restrict__ in, unsigned short* __restrict__ o, int n) {
    int i = (blockIdx.x * 256 + threadIdx.x) * 4;
    if (i < n) {
        float4 v = *reinterpret_cast<const float4*>(in + i);
        ushort4 r;
        r.x = f2b(v.x); r.y = f2b(v.y); r.z = f2b(v.z); r.w = f2b(v.w);
        *reinterpret_cast<ushort4*>(o + i) = r;
    }
}

// conv_w [k][n] -> bf16 [n][k]
__global__ void cvt_convT_k(const float* __restrict__ w, unsigned short* __restrict__ o) {
    int idx = blockIdx.x * 256 + threadIdx.x;   // 16384
    int k = idx >> 7, n = idx & 127;
    o[n * 128 + k] = f2b(w[k * 128 + n]);
}

// ---------------- MFMA bf16 GEMM (no LDS; weights L1/L2-resident) ----------------
// C[M,N] = A[M,K] @ B[N,K]^T
// MODE 0: epilogue v *= dinv[row], store bf16
// MODE 1: epilogue v = relu(v + bias[col]), store bf16
// MODE 2: epilogue v = relu(v + bias[col]), store fp32

template <int K, int MODE>
__global__ __launch_bounds__(256) void mgemm_k(
    const unsigned short* __restrict__ A, const unsigned short* __restrict__ B,
    const float* __restrict__ bias, const float* __restrict__ dinv,
    void* __restrict__ Cout, int M, int N)
{
    const int tid = threadIdx.x;
    const int wid = tid >> 6;
    const int lane = tid & 63;
    const int quad = lane >> 4;
    const int l16 = lane & 15;
    const int bm = blockIdx.x * 128 + (wid >> 1) * 64;
    const int bn = blockIdx.y * 128 + (wid & 1) * 64;

    const short8 zed = {0, 0, 0, 0, 0, 0, 0, 0};
    f32x4 acc[4][4];
#pragma unroll
    for (int i = 0; i < 4; ++i)
#pragma unroll
        for (int j = 0; j < 4; ++j) {
            f32x4 z = {0.f, 0.f, 0.f, 0.f};
            acc[i][j] = z;
        }

#pragma unroll
    for (int k0 = 0; k0 < K; k0 += 32) {
        const int ka = k0 + quad * 8;
        short8 a[4], b[4];
#pragma unroll
        for (int t = 0; t < 4; ++t) {
            int m = bm + t * 16 + l16;
            a[t] = (m < M) ? *reinterpret_cast<const short8*>(A + (size_t)m * K + ka) : zed;
            int n = bn + t * 16 + l16;
            b[t] = *reinterpret_cast<const short8*>(B + (size_t)n * K + ka);
        }
#pragma unroll
        for (int i = 0; i < 4; ++i)
#pragma unroll
            for (int j = 0; j < 4; ++j)
                acc[i][j] = __builtin_amdgcn_mfma_f32_16x16x32_bf16(a[i], b[j], acc[i][j], 0, 0, 0);
    }

    float dv[4][4];
    if (MODE == 0) {
#pragma unroll
        for (int i = 0; i < 4; ++i)
#pragma unroll
            for (int r = 0; r < 4; ++r) {
                int row = bm + i * 16 + quad * 4 + r;
                dv[i][r] = (row < M) ? dinv[row] : 0.f;
            }
    }
#pragma unroll
    for (int j = 0; j < 4; ++j) {
        int col = bn + j * 16 + l16;
        float bs = (MODE != 0) ? bias[col] : 0.f;
#pragma unroll
        for (int i = 0; i < 4; ++i)
#pragma unroll
            for (int r = 0; r < 4; ++r) {
                int row = bm + i * 16 + quad * 4 + r;
                if (row >= M) continue;
                float v = acc[i][j][r];
                if (MODE == 0) v *= dv[i][r];
                else v = fmaxf(v + bs, 0.f);
                if (MODE == 2) ((float*)Cout)[(size_t)row * N + col] = v;
                else ((unsigned short*)Cout)[(size_t)row * N + col] = f2b(v);
            }
    }
}

// ---------------- gather (bf16 rows) + fused conv epilogue ----------------
// h0[d][c] = relu( dinv[d]*(xws[d][c] + sum_in xws[src][c]) + conv_b[c] ) + x[d][c]
// 64 lanes per node, 2 channels (one packed uint) per lane.

__global__ __launch_bounds__(256) void gather_k(
    const int* __restrict__ rowptr, const int* __restrict__ csr,
    const unsigned* __restrict__ xws2, const float* __restrict__ dinv,
    const float* __restrict__ x, const float* __restrict__ conv_b,
    unsigned* __restrict__ h0)
{
    int node = blockIdx.x * 4 + (threadIdx.x >> 6);
    int lane = threadIdx.x & 63;
    if (node >= NNODES) return;
    int start = (node == 0) ? 0 : rowptr[node - 1];
    int end = rowptr[node];
    unsigned v = xws2[(size_t)node * 64 + lane];
    float s0 = b2f((unsigned short)(v & 0xffff));
    float s1 = b2f((unsigned short)(v >> 16));
    int p = start;
    while (p < end) {
        int n = end - p;
        if (n > 8) n = 8;
        int idx[8];
#pragma unroll
        for (int j = 0; j < 8; ++j)
            if (j < n) idx[j] = csr[p + j];
#pragma unroll
        for (int j = 0; j < 8; ++j)
            if (j < n) {
                unsigned w = xws2[(size_t)idx[j] * 64 + lane];
                s0 += b2f((unsigned short)(w & 0xffff));
                s1 += b2f((unsigned short)(w >> 16));
            }
        p += n;
    }
    float dvv = dinv[node];
    float2 xv = *reinterpret_cast<const float2*>(x + (size_t)node * CIN + lane * 2);
    float2 bb = *reinterpret_cast<const float2*>(conv_b + lane * 2);
    float o0 = fmaxf(s0 * dvv + bb.x, 0.f) + xv.x;
    float o1 = fmaxf(s1 * dvv + bb.y, 0.f) + xv.y;
    h0[(size_t)node * 64 + lane] = (unsigned)f2b(o0) | ((unsigned)f2b(o1) << 16);
}

// ---------------- per-graph sum + lin3 ----------------

__global__ __launch_bounds__(256) void final_k(
    const float* __restrict__ h2, const float* __restrict__ w3,
    const float* __restrict__ b3, float* __restrict__ out)
{
    int b = blockIdx.x;
    int n = threadIdx.x;
    const float* p = h2 + (size_t)b * ACT * HID + n;
    float s = 0.f;
#pragma unroll
    for (int i = 0; i < ACT; ++i) s += p[(size_t)i * HID];
    float v = s * w3[n];
    __shared__ float red[4];
#pragma unroll
    for (int off = 32; off > 0; off >>= 1) v += __shfl_down(v, off, 64);
    if ((n & 63) == 0) red[n >> 6] = v;
    __syncthreads();
    if (n == 0) out[b] = red[0] + red[1] + red[2] + red[3] + b3[0];
}

// ---------------- launch ----------------

extern "C" void kernel_launch(void* const* d_in, const int* in_sizes, int n_in,
                              void* d_out, int out_size, void* d_ws, size_t ws_size,
                              hipStream_t stream)
{
    const float* x      = (const float*)d_in[0];
    const int*   ei     = (const int*)  d_in[1];
    const float* conv_w = (const float*)d_in[2];
    const float* conv_b = (const float*)d_in[3];
    const float* lin1_w = (const float*)d_in[4];
    const float* lin1_b = (const float*)d_in[5];
    const float* lin2_w = (const float*)d_in[6];
    const float* lin2_b = (const float*)d_in[7];
    const float* lin3_w = (const float*)d_in[8];
    const float* lin3_b = (const float*)d_in[9];
    float* out = (float*)d_out;

    // Workspace layout (162 MB total):
    //   region0: h1 bf16 [N*256]                              51.2 MB
    //   region1: 102.4 MB, time-shared:
    //            phase A: xb | xws | h0  (bf16, 25.6 MB each)
    //            phase B: h2 fp32 [N*256] aliases whole region (xb/xws/h0 dead)
    //   region2: bf16 weights + CSR scratch + dinv             ~8.6 MB
    unsigned short* h1  = (unsigned short*)d_ws;                        // 25.6M ushort
    unsigned short* xb  = h1 + (size_t)25600000;                        // 12.8M
    unsigned short* xws = xb + (size_t)12800000;
    unsigned short* h0  = xws + (size_t)12800000;
    float*          h2  = (float*)xb;                                   // aliases xb..h0+pad
    unsigned short* wt0 = (unsigned short*)(xb + (size_t)51200000);     // after 102.4MB region
    unsigned short* wt1 = wt0 + 16384;
    unsigned short* wt2 = wt1 + 32768;
    int* cnt    = (int*)(wt2 + 65536);
    int* rowptr = cnt + NNODES;
    int* csr    = rowptr + NNODES;
    int* bsum   = csr + NEDGES;
    float* dinv = (float*)(bsum + 512);

    // CSR build
    zero_int_k<<<NBLK, 256, 0, stream>>>(cnt, NNODES);
    count_k<<<(NEDGES + 255) / 256, 256, 0, stream>>>(ei, cnt);
    dinv_k<<<NBLK, 256, 0, stream>>>(cnt, dinv);
    scan1_k<<<NBLK, 256, 0, stream>>>(cnt, rowptr, bsum);
    scan2_k<<<1, 512, 0, stream>>>(bsum);
    scan3_k<<<NBLK, 256, 0, stream>>>(rowptr, bsum);
    fill_k<<<(NEDGES + 255) / 256, 256, 0, stream>>>(ei, rowptr, csr);

    // bf16 conversions
    cvt_bf16_k<<<(12800000 / 4 + 255) / 256, 256, 0, stream>>>(x, xb, 12800000);
    cvt_convT_k<<<64, 256, 0, stream>>>(conv_w, wt0);
    cvt_bf16_k<<<(32768 / 4 + 255) / 256, 256, 0, stream>>>(lin1_w, wt1, 32768);
    cvt_bf16_k<<<(65536 / 4 + 255) / 256, 256, 0, stream>>>(lin2_w, wt2, 65536);

    const int gm = (NNODES + 127) / 128;   // 782

    // gemm0: xws = (x @ conv_w) * dinv[row]   (bf16 out)
    mgemm_k<128, 0><<<dim3(gm, 1), 256, 0, stream>>>(xb, wt0, nullptr, dinv, xws, NNODES, 128);

    // gather + conv epilogue -> h0 bf16
    gather_k<<<(NNODES + 3) / 4, 256, 0, stream>>>(rowptr, csr, (const unsigned*)xws,
                                                   dinv, x, conv_b, (unsigned*)h0);

    // gemm1: h1 = relu(h0 @ lin1_w^T + b1)   (bf16 out)
    mgemm_k<128, 1><<<dim3(gm, 2), 256, 0, stream>>>(h0, wt1, lin1_b, nullptr, h1, NNODES, HID);

    // gemm2: h2 = relu(h1 @ lin2_w^T + b2)   (fp32 out)
    mgemm_k<256, 2><<<dim3(gm, 2), 256, 0, stream>>>(h1, wt2, lin2_b, nullptr, h2, NNODES, HID);

    final_k<<<NGRAPH, 256, 0, stream>>>(h2, lin3_w, lin3_b, out);
}

// Round 4
// 487.089 us; speedup vs baseline: 2.6296x; 1.2439x over previous
//
#include <hip/hip_runtime.h>
#include <hip/hip_bf16.h>
#include <cstddef>

#define NNODES 100000
#define NEDGES 1600000
#define CIN 128
#define HID 256
#define ACT 20
#define NGRAPH (NNODES / ACT)
#define BSHIFT 8
#define NB ((NNODES + 255) >> 8)     // 391 buckets of 256 nodes
#define BIN_WGS 512

typedef __attribute__((ext_vector_type(8))) short short8;
typedef __attribute__((ext_vector_type(4))) float f32x4;

__device__ __forceinline__ unsigned short f2b(float f) {
    unsigned u = __float_as_uint(f);
    u += 0x7FFF + ((u >> 16) & 1);          // round-to-nearest-even
    return (unsigned short)(u >> 16);
}
__device__ __forceinline__ float b2f(unsigned short h) {
    return __uint_as_float(((unsigned)h) << 16);
}

// ---------------- bucketed CSR build ----------------

__global__ void zero_int_k(int* __restrict__ p, int n) {
    int i = blockIdx.x * 256 + threadIdx.x;
    if (i < n) p[i] = 0;
}

// per-wg LDS histogram of dst buckets
__global__ __launch_bounds__(256) void hist_k(const int* __restrict__ ei,
                                              int* __restrict__ bhist) {
    __shared__ int h[NB];
    for (int i = threadIdx.x; i < NB; i += 256) h[i] = 0;
    __syncthreads();
    const int per = (NEDGES + BIN_WGS - 1) / BIN_WGS;
    const int s = blockIdx.x * per;
    const int e = min(s + per, NEDGES);
    for (int i = s + threadIdx.x; i < e; i += 256)
        atomicAdd(&h[ei[NEDGES + i] >> BSHIFT], 1);
    __syncthreads();
    for (int i = threadIdx.x; i < NB; i += 256)
        if (h[i]) atomicAdd(&bhist[i], h[i]);
}

// single-wg exclusive scan of bhist -> bbase (and bfill working copy)
__global__ __launch_bounds__(512) void bscan_k(const int* __restrict__ bhist,
                                               int* __restrict__ bbase,
                                               int* __restrict__ bfill) {
    int i = threadIdx.x;
    int lane = i & 63, wid = i >> 6;
    int v = (i < NB) ? bhist[i] : 0;
    int inc = v;
#pragma unroll
    for (int o = 1; o < 64; o <<= 1) {
        int tv = __shfl_up(inc, o, 64);
        if (lane >= o) inc += tv;
    }
    __shared__ int wsum[8];
    if (lane == 63) wsum[wid] = inc;
    __syncthreads();
    int woff = 0;
#pragma unroll
    for (int w = 0; w < 8; ++w) woff += (w < wid) ? wsum[w] : 0;
    int excl = inc + woff - v;
    if (i < NB) { bbase[i] = excl; bfill[i] = excl; }
    if (i == NB - 1) bbase[NB] = excl + v;
}

// bin edges into bucket-contiguous (src,dst) pair runs; writes are
// per-(wg,bucket) contiguous -> coalesce in L2 (vs 64B/edge scatter).
__global__ __launch_bounds__(256) void bin_k(const int* __restrict__ ei,
                                             int* __restrict__ bfill,
                                             uint2* __restrict__ pairs) {
    __shared__ int cnt[NB], base[NB], cur[NB];
    for (int i = threadIdx.x; i < NB; i += 256) { cnt[i] = 0; cur[i] = 0; }
    __syncthreads();
    const int per = (NEDGES + BIN_WGS - 1) / BIN_WGS;
    const int s = blockIdx.x * per;
    const int e = min(s + per, NEDGES);
    for (int i = s + threadIdx.x; i < e; i += 256)
        atomicAdd(&cnt[ei[NEDGES + i] >> BSHIFT], 1);
    __syncthreads();
    for (int i = threadIdx.x; i < NB; i += 256)
        base[i] = cnt[i] ? atomicAdd(&bfill[i], cnt[i]) : 0;
    __syncthreads();
    for (int i = s + threadIdx.x; i < e; i += 256) {
        int src = ei[i], dst = ei[NEDGES + i];
        int b = dst >> BSHIFT;
        int r = atomicAdd(&cur[b], 1);
        pairs[(size_t)base[b] + r] = make_uint2((unsigned)src, (unsigned)dst);
    }
}

// one wg per bucket: count, scan, rowptr+dinv, scatter into 25KB csr window
__global__ __launch_bounds__(256) void bucket_build_k(
    const uint2* __restrict__ pairs, const int* __restrict__ bbase,
    int* __restrict__ rowptr, int* __restrict__ csr, float* __restrict__ dinv) {
    const int b = blockIdx.x;
    const int s = bbase[b], e = bbase[b + 1];
    const int node0 = b << BSHIFT;
    const int nn = min(256, NNODES - node0);
    __shared__ int cnt[256], off[256], cur[256];
    const int t = threadIdx.x;
    cnt[t] = 0; cur[t] = 0;
    __syncthreads();
    for (int i = s + t; i < e; i += 256)
        atomicAdd(&cnt[(int)pairs[i].y - node0], 1);
    __syncthreads();
    // exclusive scan of cnt[256]
    int lane = t & 63, wid = t >> 6;
    int v = cnt[t];
    int inc = v;
#pragma unroll
    for (int o = 1; o < 64; o <<= 1) {
        int tv = __shfl_up(inc, o, 64);
        if (lane >= o) inc += tv;
    }
    __shared__ int wsum[4];
    if (lane == 63) wsum[wid] = inc;
    __syncthreads();
    int woff = 0;
#pragma unroll
    for (int w = 0; w < 4; ++w) woff += (w < wid) ? wsum[w] : 0;
    int excl = inc + woff - v;
    off[t] = excl;
    if (t < nn) {
        rowptr[node0 + t] = s + excl + v;               // inclusive end
        dinv[node0 + t] = rsqrtf(1.0f + (float)v);
    }
    __syncthreads();
    for (int i = s + t; i < e; i += 256) {
        uint2 p = pairs[i];
        int loc = (int)p.y - node0;
        int r = atomicAdd(&cur[loc], 1);
        csr[s + off[loc] + r] = (int)p.x;
    }
}

// ---------------- fp32 -> bf16 conversions ----------------

__global__ void cvt_bf16_k(const float* __restrict__ in, unsigned short* __restrict__ o, int n) {
    int i = (blockIdx.x * 256 + threadIdx.x) * 4;
    if (i < n) {
        float4 v = *reinterpret_cast<const float4*>(in + i);
        ushort4 r;
        r.x = f2b(v.x); r.y = f2b(v.y); r.z = f2b(v.z); r.w = f2b(v.w);
        *reinterpret_cast<ushort4*>(o + i) = r;
    }
}

// conv_w [k][n] -> bf16 [n][k]
__global__ void cvt_convT_k(const float* __restrict__ w, unsigned short* __restrict__ o) {
    int idx = blockIdx.x * 256 + threadIdx.x;   // 16384
    int k = idx >> 7, n = idx & 127;
    o[n * 128 + k] = f2b(w[k * 128 + n]);
}

// ---------------- MFMA bf16 GEMM (no LDS; weights L1/L2-resident) ----------------
// C[M,N] = A[M,K] @ B[N,K]^T
// MODE 0: epilogue v *= dinv[row], store bf16
// MODE 1: epilogue v = relu(v + bias[col]), store bf16
// MODE 2: epilogue v = relu(v + bias[col]), store fp32

template <int K, int MODE>
__global__ __launch_bounds__(256) void mgemm_k(
    const unsigned short* __restrict__ A, const unsigned short* __restrict__ B,
    const float* __restrict__ bias, const float* __restrict__ dinv,
    void* __restrict__ Cout, int M, int N)
{
    const int tid = threadIdx.x;
    const int wid = tid >> 6;
    const int lane = tid & 63;
    const int quad = lane >> 4;
    const int l16 = lane & 15;
    const int bm = blockIdx.x * 128 + (wid >> 1) * 64;
    const int bn = blockIdx.y * 128 + (wid & 1) * 64;

    const short8 zed = {0, 0, 0, 0, 0, 0, 0, 0};
    f32x4 acc[4][4];
#pragma unroll
    for (int i = 0; i < 4; ++i)
#pragma unroll
        for (int j = 0; j < 4; ++j) {
            f32x4 z = {0.f, 0.f, 0.f, 0.f};
            acc[i][j] = z;
        }

#pragma unroll
    for (int k0 = 0; k0 < K; k0 += 32) {
        const int ka = k0 + quad * 8;
        short8 a[4], b[4];
#pragma unroll
        for (int t = 0; t < 4; ++t) {
            int m = bm + t * 16 + l16;
            a[t] = (m < M) ? *reinterpret_cast<const short8*>(A + (size_t)m * K + ka) : zed;
            int n = bn + t * 16 + l16;
            b[t] = *reinterpret_cast<const short8*>(B + (size_t)n * K + ka);
        }
#pragma unroll
        for (int i = 0; i < 4; ++i)
#pragma unroll
            for (int j = 0; j < 4; ++j)
                acc[i][j] = __builtin_amdgcn_mfma_f32_16x16x32_bf16(a[i], b[j], acc[i][j], 0, 0, 0);
    }

    float dv[4][4];
    if (MODE == 0) {
#pragma unroll
        for (int i = 0; i < 4; ++i)
#pragma unroll
            for (int r = 0; r < 4; ++r) {
                int row = bm + i * 16 + quad * 4 + r;
                dv[i][r] = (row < M) ? dinv[row] : 0.f;
            }
    }
#pragma unroll
    for (int j = 0; j < 4; ++j) {
        int col = bn + j * 16 + l16;
        float bs = (MODE != 0) ? bias[col] : 0.f;
#pragma unroll
        for (int i = 0; i < 4; ++i)
#pragma unroll
            for (int r = 0; r < 4; ++r) {
                int row = bm + i * 16 + quad * 4 + r;
                if (row >= M) continue;
                float v = acc[i][j][r];
                if (MODE == 0) v *= dv[i][r];
                else v = fmaxf(v + bs, 0.f);
                if (MODE == 2) ((float*)Cout)[(size_t)row * N + col] = v;
                else ((unsigned short*)Cout)[(size_t)row * N + col] = f2b(v);
            }
    }
}

// ---------------- gather (bf16 rows) + fused conv epilogue ----------------

__global__ __launch_bounds__(256) void gather_k(
    const int* __restrict__ rowptr, const int* __restrict__ csr,
    const unsigned* __restrict__ xws2, const float* __restrict__ dinv,
    const float* __restrict__ x, const float* __restrict__ conv_b,
    unsigned* __restrict__ h0)
{
    int node = blockIdx.x * 4 + (threadIdx.x >> 6);
    int lane = threadIdx.x & 63;
    if (node >= NNODES) return;
    int start = (node == 0) ? 0 : rowptr[node - 1];
    int end = rowptr[node];
    unsigned v = xws2[(size_t)node * 64 + lane];
    float s0 = b2f((unsigned short)(v & 0xffff));
    float s1 = b2f((unsigned short)(v >> 16));
    int p = start;
    while (p < end) {
        int n = end - p;
        if (n > 8) n = 8;
        int idx[8];
#pragma unroll
        for (int j = 0; j < 8; ++j)
            if (j < n) idx[j] = csr[p + j];
#pragma unroll
        for (int j = 0; j < 8; ++j)
            if (j < n) {
                unsigned w = xws2[(size_t)idx[j] * 64 + lane];
                s0 += b2f((unsigned short)(w & 0xffff));
                s1 += b2f((unsigned short)(w >> 16));
            }
        p += n;
    }
    float dvv = dinv[node];
    float2 xv = *reinterpret_cast<const float2*>(x + (size_t)node * CIN + lane * 2);
    float2 bb = *reinterpret_cast<const float2*>(conv_b + lane * 2);
    float o0 = fmaxf(s0 * dvv + bb.x, 0.f) + xv.x;
    float o1 = fmaxf(s1 * dvv + bb.y, 0.f) + xv.y;
    h0[(size_t)node * 64 + lane] = (unsigned)f2b(o0) | ((unsigned)f2b(o1) << 16);
}

// ---------------- per-graph sum + lin3 ----------------

__global__ __launch_bounds__(256) void final_k(
    const float* __restrict__ h2, const float* __restrict__ w3,
    const float* __restrict__ b3, float* __restrict__ out)
{
    int b = blockIdx.x;
    int n = threadIdx.x;
    const float* p = h2 + (size_t)b * ACT * HID + n;
    float s = 0.f;
#pragma unroll
    for (int i = 0; i < ACT; ++i) s += p[(size_t)i * HID];
    float v = s * w3[n];
    __shared__ float red[4];
#pragma unroll
    for (int off = 32; off > 0; off >>= 1) v += __shfl_down(v, off, 64);
    if ((n & 63) == 0) red[n >> 6] = v;
    __syncthreads();
    if (n == 0) out[b] = red[0] + red[1] + red[2] + red[3] + b3[0];
}

// ---------------- launch ----------------

extern "C" void kernel_launch(void* const* d_in, const int* in_sizes, int n_in,
                              void* d_out, int out_size, void* d_ws, size_t ws_size,
                              hipStream_t stream)
{
    const float* x      = (const float*)d_in[0];
    const int*   ei     = (const int*)  d_in[1];
    const float* conv_w = (const float*)d_in[2];
    const float* conv_b = (const float*)d_in[3];
    const float* lin1_w = (const float*)d_in[4];
    const float* lin1_b = (const float*)d_in[5];
    const float* lin2_w = (const float*)d_in[6];
    const float* lin2_b = (const float*)d_in[7];
    const float* lin3_w = (const float*)d_in[8];
    const float* lin3_b = (const float*)d_in[9];
    float* out = (float*)d_out;

    // Workspace (~161 MB):
    //   region0: h1 bf16 [N*256]                               51.2 MB
    //   region1 (102.4 MB): phase A = xb | xws | h0 | pairs(12.8MB in spare);
    //                       phase B = h2 fp32 [N*256] aliases all of it
    //   tail: bf16 weights, rowptr, csr, dinv, bucket arrays
    unsigned short* h1  = (unsigned short*)d_ws;                     // 25.6M ushort
    unsigned short* xb  = h1 + (size_t)25600000;
    unsigned short* xws = xb + (size_t)12800000;
    unsigned short* h0  = xws + (size_t)12800000;
    uint2*          pairs = (uint2*)(xb + (size_t)38400000);         // 12.8 MB spare
    float*          h2  = (float*)xb;
    unsigned short* wt0 = xb + (size_t)51200000;                     // region1 end
    unsigned short* wt1 = wt0 + 16384;
    unsigned short* wt2 = wt1 + 32768;
    int*   rowptr = (int*)(wt2 + 65536);
    int*   csr    = rowptr + NNODES;
    float* dinv   = (float*)(csr + NEDGES);
    int*   bhist  = (int*)(dinv + NNODES);
    int*   bbase  = bhist + NB;
    int*   bfill  = bbase + NB + 1;

    // CSR build (bucketed, no global random scatter)
    zero_int_k<<<(NB + 255) / 256, 256, 0, stream>>>(bhist, NB);
    hist_k<<<BIN_WGS, 256, 0, stream>>>(ei, bhist);
    bscan_k<<<1, 512, 0, stream>>>(bhist, bbase, bfill);
    bin_k<<<BIN_WGS, 256, 0, stream>>>(ei, bfill, pairs);
    bucket_build_k<<<NB, 256, 0, stream>>>(pairs, bbase, rowptr, csr, dinv);

    // bf16 conversions
    cvt_bf16_k<<<(12800000 / 4 + 255) / 256, 256, 0, stream>>>(x, xb, 12800000);
    cvt_convT_k<<<64, 256, 0, stream>>>(conv_w, wt0);
    cvt_bf16_k<<<(32768 / 4 + 255) / 256, 256, 0, stream>>>(lin1_w, wt1, 32768);
    cvt_bf16_k<<<(65536 / 4 + 255) / 256, 256, 0, stream>>>(lin2_w, wt2, 65536);

    const int gm = (NNODES + 127) / 128;   // 782

    // gemm0: xws = (x @ conv_w) * dinv[row]   (bf16 out)
    mgemm_k<128, 0><<<dim3(gm, 1), 256, 0, stream>>>(xb, wt0, nullptr, dinv, xws, NNODES, 128);

    // gather + conv epilogue -> h0 bf16
    gather_k<<<(NNODES + 3) / 4, 256, 0, stream>>>(rowptr, csr, (const unsigned*)xws,
                                                   dinv, x, conv_b, (unsigned*)h0);

    // gemm1: h1 = relu(h0 @ lin1_w^T + b1)   (bf16 out)
    mgemm_k<128, 1><<<dim3(gm, 2), 256, 0, stream>>>(h0, wt1, lin1_b, nullptr, h1, NNODES, HID);

    // gemm2: h2 = relu(h1 @ lin2_w^T + b2)   (fp32 out)
    mgemm_k<256, 2><<<dim3(gm, 2), 256, 0, stream>>>(h1, wt2, lin2_b, nullptr, h2, NNODES, HID);

    final_k<<<NGRAPH, 256, 0, stream>>>(h2, lin3_w, lin3_b, out);
}

// Round 5
// 434.701 us; speedup vs baseline: 2.9465x; 1.1205x over previous
//
#include <hip/hip_runtime.h>
#include <hip/hip_bf16.h>
#include <cstddef>

#define NNODES 100000
#define NEDGES 1600000
#define CIN 128
#define HID 256
#define ACT 20
#define NGRAPH (NNODES / ACT)
#define BSHIFT 8
#define NB ((NNODES + 255) >> 8)     // 391 buckets of 256 nodes
#define BIN_WGS 512

typedef __attribute__((ext_vector_type(8))) short short8;
typedef __attribute__((ext_vector_type(4))) float f32x4;

__device__ __forceinline__ unsigned short f2b(float f) {
    unsigned u = __float_as_uint(f);
    u += 0x7FFF + ((u >> 16) & 1);          // round-to-nearest-even
    return (unsigned short)(u >> 16);
}
__device__ __forceinline__ float b2f(unsigned short h) {
    return __uint_as_float(((unsigned)h) << 16);
}

// ---------------- bucketed CSR build ----------------

// per-wg LDS histogram of dst buckets
__global__ __launch_bounds__(256) void hist_k(const int* __restrict__ ei,
                                              int* __restrict__ bhist) {
    __shared__ int h[NB];
    for (int i = threadIdx.x; i < NB; i += 256) h[i] = 0;
    __syncthreads();
    const int per = (NEDGES + BIN_WGS - 1) / BIN_WGS;
    const int s = blockIdx.x * per;
    const int e = min(s + per, NEDGES);
    for (int i = s + threadIdx.x; i < e; i += 256)
        atomicAdd(&h[ei[NEDGES + i] >> BSHIFT], 1);
    __syncthreads();
    for (int i = threadIdx.x; i < NB; i += 256)
        if (h[i]) atomicAdd(&bhist[i], h[i]);
}

// single-wg exclusive scan of bhist -> bbase (and bfill working copy)
__global__ __launch_bounds__(512) void bscan_k(const int* __restrict__ bhist,
                                               int* __restrict__ bbase,
                                               int* __restrict__ bfill) {
    int i = threadIdx.x;
    int lane = i & 63, wid = i >> 6;
    int v = (i < NB) ? bhist[i] : 0;
    int inc = v;
#pragma unroll
    for (int o = 1; o < 64; o <<= 1) {
        int tv = __shfl_up(inc, o, 64);
        if (lane >= o) inc += tv;
    }
    __shared__ int wsum[8];
    if (lane == 63) wsum[wid] = inc;
    __syncthreads();
    int woff = 0;
#pragma unroll
    for (int w = 0; w < 8; ++w) woff += (w < wid) ? wsum[w] : 0;
    int excl = inc + woff - v;
    if (i < NB) { bbase[i] = excl; bfill[i] = excl; }
    if (i == NB - 1) bbase[NB] = excl + v;
}

// bin edges into bucket-contiguous (src,dst) pair runs
__global__ __launch_bounds__(256) void bin_k(const int* __restrict__ ei,
                                             int* __restrict__ bfill,
                                             uint2* __restrict__ pairs) {
    __shared__ int cnt[NB], base[NB], cur[NB];
    for (int i = threadIdx.x; i < NB; i += 256) { cnt[i] = 0; cur[i] = 0; }
    __syncthreads();
    const int per = (NEDGES + BIN_WGS - 1) / BIN_WGS;
    const int s = blockIdx.x * per;
    const int e = min(s + per, NEDGES);
    for (int i = s + threadIdx.x; i < e; i += 256)
        atomicAdd(&cnt[ei[NEDGES + i] >> BSHIFT], 1);
    __syncthreads();
    for (int i = threadIdx.x; i < NB; i += 256)
        base[i] = cnt[i] ? atomicAdd(&bfill[i], cnt[i]) : 0;
    __syncthreads();
    for (int i = s + threadIdx.x; i < e; i += 256) {
        int src = ei[i], dst = ei[NEDGES + i];
        int b = dst >> BSHIFT;
        int r = atomicAdd(&cur[b], 1);
        pairs[(size_t)base[b] + r] = make_uint2((unsigned)src, (unsigned)dst);
    }
}

// one wg per bucket: count, scan, rowptr+dinv, scatter into 25KB csr window
__global__ __launch_bounds__(256) void bucket_build_k(
    const uint2* __restrict__ pairs, const int* __restrict__ bbase,
    int* __restrict__ rowptr, int* __restrict__ csr, float* __restrict__ dinv) {
    const int b = blockIdx.x;
    const int s = bbase[b], e = bbase[b + 1];
    const int node0 = b << BSHIFT;
    const int nn = min(256, NNODES - node0);
    __shared__ int cnt[256], off[256], cur[256];
    const int t = threadIdx.x;
    cnt[t] = 0; cur[t] = 0;
    __syncthreads();
    for (int i = s + t; i < e; i += 256)
        atomicAdd(&cnt[(int)pairs[i].y - node0], 1);
    __syncthreads();
    int lane = t & 63, wid = t >> 6;
    int v = cnt[t];
    int inc = v;
#pragma unroll
    for (int o = 1; o < 64; o <<= 1) {
        int tv = __shfl_up(inc, o, 64);
        if (lane >= o) inc += tv;
    }
    __shared__ int wsum[4];
    if (lane == 63) wsum[wid] = inc;
    __syncthreads();
    int woff = 0;
#pragma unroll
    for (int w = 0; w < 4; ++w) woff += (w < wid) ? wsum[w] : 0;
    int excl = inc + woff - v;
    off[t] = excl;
    if (t < nn) {
        rowptr[node0 + t] = s + excl + v;               // inclusive end
        dinv[node0 + t] = rsqrtf(1.0f + (float)v);
    }
    __syncthreads();
    for (int i = s + t; i < e; i += 256) {
        uint2 p = pairs[i];
        int loc = (int)p.y - node0;
        int r = atomicAdd(&cur[loc], 1);
        csr[s + off[loc] + r] = (int)p.x;
    }
}

// ---------------- weight conversions (single launch) ----------------
// wt0 = conv_w [k][n] -> bf16 [n][k]; wt1/wt2 straight copies

__global__ void cvt_w_k(const float* __restrict__ conv_w,
                        const float* __restrict__ lin1_w,
                        const float* __restrict__ lin2_w,
                        unsigned short* __restrict__ wt0,
                        unsigned short* __restrict__ wt1,
                        unsigned short* __restrict__ wt2) {
    int id = blockIdx.x * 256 + threadIdx.x;
    if (id < 16384) {
        int k = id >> 7, n = id & 127;
        wt0[n * 128 + k] = f2b(conv_w[k * 128 + n]);
    } else if (id < 16384 + 32768) {
        int i = id - 16384;
        wt1[i] = f2b(lin1_w[i]);
    } else if (id < 16384 + 32768 + 65536) {
        int i = id - 49152;
        wt2[i] = f2b(lin2_w[i]);
    }
}

// ---------------- MFMA bf16 GEMM (no LDS; weights L1/L2-resident) ----------------
// C[M,N] = A[M,K] @ B[N,K]^T
// AF32: A is fp32, converted in-register (saves a separate conversion pass)
// MODE 0: epilogue v *= dinv[row], store bf16
// MODE 1: epilogue v = relu(v + bias[col]), store bf16
// MODE 2: epilogue v = relu(v + bias[col]), store fp32

template <int K, int MODE, int AF32>
__global__ __launch_bounds__(256) void mgemm_k(
    const void* __restrict__ Ain, const unsigned short* __restrict__ B,
    const float* __restrict__ bias, const float* __restrict__ dinv,
    void* __restrict__ Cout, int M, int N)
{
    const int tid = threadIdx.x;
    const int wid = tid >> 6;
    const int lane = tid & 63;
    const int quad = lane >> 4;
    const int l16 = lane & 15;
    const int bm = blockIdx.x * 128 + (wid >> 1) * 64;
    const int bn = blockIdx.y * 128 + (wid & 1) * 64;

    const short8 zed = {0, 0, 0, 0, 0, 0, 0, 0};
    f32x4 acc[4][4];
#pragma unroll
    for (int i = 0; i < 4; ++i)
#pragma unroll
        for (int j = 0; j < 4; ++j) {
            f32x4 z = {0.f, 0.f, 0.f, 0.f};
            acc[i][j] = z;
        }

#pragma unroll
    for (int k0 = 0; k0 < K; k0 += 32) {
        const int ka = k0 + quad * 8;
        short8 a[4], b[4];
#pragma unroll
        for (int t = 0; t < 4; ++t) {
            int m = bm + t * 16 + l16;
            if (AF32) {
                short8 av = zed;
                if (m < M) {
                    const float* Af = (const float*)Ain;
                    float4 f0 = *reinterpret_cast<const float4*>(Af + (size_t)m * K + ka);
                    float4 f1 = *reinterpret_cast<const float4*>(Af + (size_t)m * K + ka + 4);
                    av[0] = (short)f2b(f0.x); av[1] = (short)f2b(f0.y);
                    av[2] = (short)f2b(f0.z); av[3] = (short)f2b(f0.w);
                    av[4] = (short)f2b(f1.x); av[5] = (short)f2b(f1.y);
                    av[6] = (short)f2b(f1.z); av[7] = (short)f2b(f1.w);
                }
                a[t] = av;
            } else {
                const unsigned short* Ab = (const unsigned short*)Ain;
                a[t] = (m < M) ? *reinterpret_cast<const short8*>(Ab + (size_t)m * K + ka) : zed;
            }
            int n = bn + t * 16 + l16;
            b[t] = *reinterpret_cast<const short8*>(B + (size_t)n * K + ka);
        }
#pragma unroll
        for (int i = 0; i < 4; ++i)
#pragma unroll
            for (int j = 0; j < 4; ++j)
                acc[i][j] = __builtin_amdgcn_mfma_f32_16x16x32_bf16(a[i], b[j], acc[i][j], 0, 0, 0);
    }

    float dv[4][4];
    if (MODE == 0) {
#pragma unroll
        for (int i = 0; i < 4; ++i)
#pragma unroll
            for (int r = 0; r < 4; ++r) {
                int row = bm + i * 16 + quad * 4 + r;
                dv[i][r] = (row < M) ? dinv[row] : 0.f;
            }
    }
#pragma unroll
    for (int j = 0; j < 4; ++j) {
        int col = bn + j * 16 + l16;
        float bs = (MODE != 0) ? bias[col] : 0.f;
#pragma unroll
        for (int i = 0; i < 4; ++i)
#pragma unroll
            for (int r = 0; r < 4; ++r) {
                int row = bm + i * 16 + quad * 4 + r;
                if (row >= M) continue;
                float v = acc[i][j][r];
                if (MODE == 0) v *= dv[i][r];
                else v = fmaxf(v + bs, 0.f);
                if (MODE == 2) ((float*)Cout)[(size_t)row * N + col] = v;
                else ((unsigned short*)Cout)[(size_t)row * N + col] = f2b(v);
            }
    }
}

// ---------------- gather v3: 4 rows per wave-load (1 KB/instr) ----------------
// One wave per node. 16 lanes cover one 256B row (dwordx4 each);
// the 4 sub-groups (lane>>4) fetch 4 different source rows concurrently,
// 16 rows in flight per iteration. Final shfl_xor reduction across subs.
// h0[d][c] = relu( dinv[d]*(xws[d][c] + sum_in xws[src][c]) + conv_b[c] ) + x[d][c]

__global__ __launch_bounds__(256) void gather_k(
    const int* __restrict__ rowptr, const int* __restrict__ csr,
    const unsigned short* __restrict__ xws, const float* __restrict__ dinv,
    const float* __restrict__ x, const float* __restrict__ conv_b,
    unsigned short* __restrict__ h0)
{
    const int node = blockIdx.x * 4 + (threadIdx.x >> 6);
    if (node >= NNODES) return;
    const int lane = threadIdx.x & 63;
    const int sub = lane >> 4;       // 0..3: which row of the 4-in-flight
    const int c16 = lane & 15;       // 8-channel group within the row

    const int start = (node == 0) ? 0 : rowptr[node - 1];
    const int end = rowptr[node];

    float s[8];
    // self row (once, sub-group 0 only)
    if (sub == 0) {
        short8 r = *reinterpret_cast<const short8*>(xws + (size_t)node * CIN + c16 * 8);
#pragma unroll
        for (int q = 0; q < 8; ++q) s[q] = b2f((unsigned short)r[q]);
    } else {
#pragma unroll
        for (int q = 0; q < 8; ++q) s[q] = 0.f;
    }

    for (int p = start; p < end; p += 16) {
        short8 r[4];
        int valid[4];
#pragma unroll
        for (int j = 0; j < 4; ++j) {
            int e = p + j * 4 + sub;
            bool a = e < end;
            int idx = a ? csr[e] : node;     // safe fallback, not accumulated
            r[j] = *reinterpret_cast<const short8*>(xws + (size_t)idx * CIN + c16 * 8);
            valid[j] = a;
        }
#pragma unroll
        for (int j = 0; j < 4; ++j)
            if (valid[j]) {
#pragma unroll
                for (int q = 0; q < 8; ++q) s[q] += b2f((unsigned short)r[j][q]);
            }
    }

    // reduce across the 4 sub-groups (lanes differing in bits 4,5)
#pragma unroll
    for (int q = 0; q < 8; ++q) {
        s[q] += __shfl_xor(s[q], 16, 64);
        s[q] += __shfl_xor(s[q], 32, 64);
    }

    if (sub == 0) {
        float dvv = dinv[node];
        float4 b0 = *reinterpret_cast<const float4*>(conv_b + c16 * 8);
        float4 b1 = *reinterpret_cast<const float4*>(conv_b + c16 * 8 + 4);
        float4 x0 = *reinterpret_cast<const float4*>(x + (size_t)node * CIN + c16 * 8);
        float4 x1 = *reinterpret_cast<const float4*>(x + (size_t)node * CIN + c16 * 8 + 4);
        float o[8];
        o[0] = fmaxf(s[0] * dvv + b0.x, 0.f) + x0.x;
        o[1] = fmaxf(s[1] * dvv + b0.y, 0.f) + x0.y;
        o[2] = fmaxf(s[2] * dvv + b0.z, 0.f) + x0.z;
        o[3] = fmaxf(s[3] * dvv + b0.w, 0.f) + x0.w;
        o[4] = fmaxf(s[4] * dvv + b1.x, 0.f) + x1.x;
        o[5] = fmaxf(s[5] * dvv + b1.y, 0.f) + x1.y;
        o[6] = fmaxf(s[6] * dvv + b1.z, 0.f) + x1.z;
        o[7] = fmaxf(s[7] * dvv + b1.w, 0.f) + x1.w;
        short8 pk;
#pragma unroll
        for (int q = 0; q < 8; ++q) pk[q] = (short)f2b(o[q]);
        *reinterpret_cast<short8*>(h0 + (size_t)node * CIN + c16 * 8) = pk;
    }
}

// ---------------- per-graph sum + lin3 ----------------

__global__ __launch_bounds__(256) void final_k(
    const float* __restrict__ h2, const float* __restrict__ w3,
    const float* __restrict__ b3, float* __restrict__ out)
{
    int b = blockIdx.x;
    int n = threadIdx.x;
    const float* p = h2 + (size_t)b * ACT * HID + n;
    float s = 0.f;
#pragma unroll
    for (int i = 0; i < ACT; ++i) s += p[(size_t)i * HID];
    float v = s * w3[n];
    __shared__ float red[4];
#pragma unroll
    for (int off = 32; off > 0; off >>= 1) v += __shfl_down(v, off, 64);
    if ((n & 63) == 0) red[n >> 6] = v;
    __syncthreads();
    if (n == 0) out[b] = red[0] + red[1] + red[2] + red[3] + b3[0];
}

// ---------------- launch ----------------

extern "C" void kernel_launch(void* const* d_in, const int* in_sizes, int n_in,
                              void* d_out, int out_size, void* d_ws, size_t ws_size,
                              hipStream_t stream)
{
    const float* x      = (const float*)d_in[0];
    const int*   ei     = (const int*)  d_in[1];
    const float* conv_w = (const float*)d_in[2];
    const float* conv_b = (const float*)d_in[3];
    const float* lin1_w = (const float*)d_in[4];
    const float* lin1_b = (const float*)d_in[5];
    const float* lin2_w = (const float*)d_in[6];
    const float* lin2_b = (const float*)d_in[7];
    const float* lin3_w = (const float*)d_in[8];
    const float* lin3_b = (const float*)d_in[9];
    float* out = (float*)d_out;

    // Workspace (~161 MB):
    //   region0: h1 bf16 [N*256]                               51.2 MB
    //   region1 (102.4 MB): phase A = xws | h0 | pairs (25.6+25.6+12.8 MB);
    //                       phase B = h2 fp32 [N*256] aliases all of it
    //   tail: bf16 weights, rowptr, csr, dinv, bucket arrays
    unsigned short* h1    = (unsigned short*)d_ws;                   // 25.6M ushort
    unsigned short* xws   = h1 + (size_t)25600000;                   // region1 start
    unsigned short* h0    = xws + (size_t)12800000;
    uint2*          pairs = (uint2*)(h0 + (size_t)12800000);         // 12.8 MB
    float*          h2    = (float*)xws;
    unsigned short* wt0   = xws + (size_t)51200000;                  // region1 end
    unsigned short* wt1   = wt0 + 16384;
    unsigned short* wt2   = wt1 + 32768;
    int*   rowptr = (int*)(wt2 + 65536);
    int*   csr    = rowptr + NNODES;
    float* dinv   = (float*)(csr + NEDGES);
    int*   bhist  = (int*)(dinv + NNODES);
    int*   bbase  = bhist + NB;
    int*   bfill  = bbase + NB + 1;

    // CSR build (bucketed, no global random scatter)
    hipMemsetAsync(bhist, 0, NB * sizeof(int), stream);
    hist_k<<<BIN_WGS, 256, 0, stream>>>(ei, bhist);
    bscan_k<<<1, 512, 0, stream>>>(bhist, bbase, bfill);
    bin_k<<<BIN_WGS, 256, 0, stream>>>(ei, bfill, pairs);
    bucket_build_k<<<NB, 256, 0, stream>>>(pairs, bbase, rowptr, csr, dinv);

    // weight conversions (one launch)
    cvt_w_k<<<(114688 + 255) / 256, 256, 0, stream>>>(conv_w, lin1_w, lin2_w, wt0, wt1, wt2);

    const int gm = (NNODES + 127) / 128;   // 782

    // gemm0: xws = (x @ conv_w) * dinv[row]   (fp32 A in-register cvt, bf16 out)
    mgemm_k<128, 0, 1><<<dim3(gm, 1), 256, 0, stream>>>(x, wt0, nullptr, dinv, xws, NNODES, 128);

    // gather + conv epilogue -> h0 bf16
    gather_k<<<(NNODES + 3) / 4, 256, 0, stream>>>(rowptr, csr, xws, dinv, x, conv_b, h0);

    // gemm1: h1 = relu(h0 @ lin1_w^T + b1)   (bf16 out)
    mgemm_k<128, 1, 0><<<dim3(gm, 2), 256, 0, stream>>>(h0, wt1, lin1_b, nullptr, h1, NNODES, HID);

    // gemm2: h2 = relu(h1 @ lin2_w^T + b2)   (fp32 out)
    mgemm_k<256, 2, 0><<<dim3(gm, 2), 256, 0, stream>>>(h1, wt2, lin2_b, nullptr, h2, NNODES, HID);

    final_k<<<NGRAPH, 256, 0, stream>>>(h2, lin3_w, lin3_b, out);
}

// Round 6
// 397.289 us; speedup vs baseline: 3.2239x; 1.0942x over previous
//
#include <hip/hip_runtime.h>
#include <hip/hip_bf16.h>
#include <cstddef>

#define NNODES 100000
#define NEDGES 1600000
#define CIN 128
#define HID 256
#define ACT 20
#define NGRAPH (NNODES / ACT)
#define BSHIFT 8
#define NB ((NNODES + 255) >> 8)     // 391 buckets of 256 nodes
#define BIN_WGS 512
#define CAP 8192                     // bucket window capacity (mean fill 4096)

typedef __attribute__((ext_vector_type(8))) short short8;
typedef __attribute__((ext_vector_type(4))) float f32x4;

__device__ __forceinline__ unsigned short f2b(float f) {
    unsigned u = __float_as_uint(f);
    u += 0x7FFF + ((u >> 16) & 1);          // round-to-nearest-even
    return (unsigned short)(u >> 16);
}
__device__ __forceinline__ float b2f(unsigned short h) {
    return __uint_as_float(((unsigned)h) << 16);
}

// ---------------- bucketed CSR build (fixed-capacity windows) ----------------
// entries[b*CAP + i] = (src << 8) | (dst & 255); bfill[b] = bucket fill count.

__global__ __launch_bounds__(256) void bin_k(const int* __restrict__ ei,
                                             int* __restrict__ bfill,
                                             unsigned* __restrict__ entries) {
    __shared__ int cnt[NB], base[NB], cur[NB];
    for (int i = threadIdx.x; i < NB; i += 256) { cnt[i] = 0; cur[i] = 0; }
    __syncthreads();
    const int per = NEDGES / BIN_WGS;      // 3125
    const int s = blockIdx.x * per;
    const int e = s + per;
    for (int i = s + threadIdx.x; i < e; i += 256)
        atomicAdd(&cnt[ei[NEDGES + i] >> BSHIFT], 1);
    __syncthreads();
    for (int i = threadIdx.x; i < NB; i += 256)
        base[i] = cnt[i] ? atomicAdd(&bfill[i], cnt[i]) : 0;
    __syncthreads();
    for (int i = s + threadIdx.x; i < e; i += 256) {
        int src = ei[i], dst = ei[NEDGES + i];
        int b = dst >> BSHIFT;
        int r = base[b] + atomicAdd(&cur[b], 1);
        if (r < CAP)
            entries[(size_t)b * CAP + r] = ((unsigned)src << 8) | (unsigned)(dst & 255);
    }
}

// one wg per bucket: count, scan, rowptr2+dinv, scatter into padded csr window
__global__ __launch_bounds__(256) void bucket_build_k(
    const unsigned* __restrict__ entries, const int* __restrict__ bfill,
    int2* __restrict__ rowptr2, int* __restrict__ csr, float* __restrict__ dinv) {
    const int b = blockIdx.x;
    const int count = min(bfill[b], CAP);
    const int node0 = b << BSHIFT;
    const int nn = min(256, NNODES - node0);
    const size_t gbase = (size_t)b * CAP;
    __shared__ int cnt[256], off[256], cur[256];
    const int t = threadIdx.x;
    cnt[t] = 0; cur[t] = 0;
    __syncthreads();
    for (int i = t; i < count; i += 256)
        atomicAdd(&cnt[entries[gbase + i] & 255], 1);
    __syncthreads();
    int lane = t & 63, wid = t >> 6;
    int v = cnt[t];
    int inc = v;
#pragma unroll
    for (int o = 1; o < 64; o <<= 1) {
        int tv = __shfl_up(inc, o, 64);
        if (lane >= o) inc += tv;
    }
    __shared__ int wsum[4];
    if (lane == 63) wsum[wid] = inc;
    __syncthreads();
    int woff = 0;
#pragma unroll
    for (int w = 0; w < 4; ++w) woff += (w < wid) ? wsum[w] : 0;
    int excl = inc + woff - v;
    off[t] = excl;
    if (t < nn) {
        rowptr2[node0 + t] = make_int2((int)gbase + excl, (int)gbase + excl + v);
        dinv[node0 + t] = rsqrtf(1.0f + (float)v);
    }
    __syncthreads();
    for (int i = t; i < count; i += 256) {
        unsigned en = entries[gbase + i];
        int loc = (int)(en & 255);
        int r = atomicAdd(&cur[loc], 1);
        csr[gbase + off[loc] + r] = (int)(en >> 8);
    }
}

// ---------------- weight conversions (single launch) ----------------
// wt0 = conv_w [k][n] -> bf16 [n][k]; wt1/wt2 straight copies

__global__ void cvt_w_k(const float* __restrict__ conv_w,
                        const float* __restrict__ lin1_w,
                        const float* __restrict__ lin2_w,
                        unsigned short* __restrict__ wt0,
                        unsigned short* __restrict__ wt1,
                        unsigned short* __restrict__ wt2) {
    int id = blockIdx.x * 256 + threadIdx.x;
    if (id < 16384) {
        int k = id >> 7, n = id & 127;
        wt0[n * 128 + k] = f2b(conv_w[k * 128 + n]);
    } else if (id < 16384 + 32768) {
        int i = id - 16384;
        wt1[i] = f2b(lin1_w[i]);
    } else if (id < 16384 + 32768 + 65536) {
        int i = id - 49152;
        wt2[i] = f2b(lin2_w[i]);
    }
}

// ---------------- MFMA bf16 GEMM for conv (fp32 A in-register cvt) ----------
// xws[M,128] = (A[M,128] @ B[128,128]^T) * dinv[row], bf16 out

__global__ __launch_bounds__(256) void mgemm0_k(
    const float* __restrict__ Af, const unsigned short* __restrict__ B,
    const float* __restrict__ dinv, unsigned short* __restrict__ Cout, int M)
{
    const int tid = threadIdx.x;
    const int wid = tid >> 6;
    const int lane = tid & 63;
    const int quad = lane >> 4;
    const int l16 = lane & 15;
    const int bm = blockIdx.x * 128 + (wid >> 1) * 64;
    const int bn = (wid & 1) * 64;

    const short8 zed = {0, 0, 0, 0, 0, 0, 0, 0};
    f32x4 acc[4][4];
#pragma unroll
    for (int i = 0; i < 4; ++i)
#pragma unroll
        for (int j = 0; j < 4; ++j) {
            f32x4 z = {0.f, 0.f, 0.f, 0.f};
            acc[i][j] = z;
        }

#pragma unroll
    for (int k0 = 0; k0 < 128; k0 += 32) {
        const int ka = k0 + quad * 8;
        short8 a[4], b[4];
#pragma unroll
        for (int t = 0; t < 4; ++t) {
            int m = bm + t * 16 + l16;
            short8 av = zed;
            if (m < M) {
                float4 f0 = *reinterpret_cast<const float4*>(Af + (size_t)m * 128 + ka);
                float4 f1 = *reinterpret_cast<const float4*>(Af + (size_t)m * 128 + ka + 4);
                av[0] = (short)f2b(f0.x); av[1] = (short)f2b(f0.y);
                av[2] = (short)f2b(f0.z); av[3] = (short)f2b(f0.w);
                av[4] = (short)f2b(f1.x); av[5] = (short)f2b(f1.y);
                av[6] = (short)f2b(f1.z); av[7] = (short)f2b(f1.w);
            }
            a[t] = av;
            int n = bn + t * 16 + l16;
            b[t] = *reinterpret_cast<const short8*>(B + (size_t)n * 128 + ka);
        }
#pragma unroll
        for (int i = 0; i < 4; ++i)
#pragma unroll
            for (int j = 0; j < 4; ++j)
                acc[i][j] = __builtin_amdgcn_mfma_f32_16x16x32_bf16(a[i], b[j], acc[i][j], 0, 0, 0);
    }

#pragma unroll
    for (int i = 0; i < 4; ++i)
#pragma unroll
        for (int r = 0; r < 4; ++r) {
            int row = bm + i * 16 + quad * 4 + r;
            if (row >= M) continue;
            float dv = dinv[row];
#pragma unroll
            for (int j = 0; j < 4; ++j) {
                int col = bn + j * 16 + l16;
                Cout[(size_t)row * 128 + col] = f2b(acc[i][j][r] * dv);
            }
        }
}

// ---------------- gather v4: 4 rows per wave-load, padded CSR ----------------
// h0[d][c] = relu( dinv[d]*(xws[d][c] + sum_in xws[src][c]) + conv_b[c] ) + x[d][c]

__global__ __launch_bounds__(256) void gather_k(
    const int2* __restrict__ rowptr2, const int* __restrict__ csr,
    const unsigned short* __restrict__ xws, const float* __restrict__ dinv,
    const float* __restrict__ x, const float* __restrict__ conv_b,
    unsigned short* __restrict__ h0)
{
    const int node = blockIdx.x * 4 + (threadIdx.x >> 6);
    if (node >= NNODES) return;
    const int lane = threadIdx.x & 63;
    const int sub = lane >> 4;
    const int c16 = lane & 15;

    const int2 se = rowptr2[node];
    const int start = se.x, end = se.y;

    float s[8];
    if (sub == 0) {
        short8 r = *reinterpret_cast<const short8*>(xws + (size_t)node * CIN + c16 * 8);
#pragma unroll
        for (int q = 0; q < 8; ++q) s[q] = b2f((unsigned short)r[q]);
    } else {
#pragma unroll
        for (int q = 0; q < 8; ++q) s[q] = 0.f;
    }

    for (int p = start; p < end; p += 16) {
        short8 r[4];
        int valid[4];
#pragma unroll
        for (int j = 0; j < 4; ++j) {
            int e = p + j * 4 + sub;
            bool a = e < end;
            int idx = a ? csr[e] : node;
            r[j] = *reinterpret_cast<const short8*>(xws + (size_t)idx * CIN + c16 * 8);
            valid[j] = a;
        }
#pragma unroll
        for (int j = 0; j < 4; ++j)
            if (valid[j]) {
#pragma unroll
                for (int q = 0; q < 8; ++q) s[q] += b2f((unsigned short)r[j][q]);
            }
    }

#pragma unroll
    for (int q = 0; q < 8; ++q) {
        s[q] += __shfl_xor(s[q], 16, 64);
        s[q] += __shfl_xor(s[q], 32, 64);
    }

    if (sub == 0) {
        float dvv = dinv[node];
        float4 b0 = *reinterpret_cast<const float4*>(conv_b + c16 * 8);
        float4 b1 = *reinterpret_cast<const float4*>(conv_b + c16 * 8 + 4);
        float4 x0 = *reinterpret_cast<const float4*>(x + (size_t)node * CIN + c16 * 8);
        float4 x1 = *reinterpret_cast<const float4*>(x + (size_t)node * CIN + c16 * 8 + 4);
        float o[8];
        o[0] = fmaxf(s[0] * dvv + b0.x, 0.f) + x0.x;
        o[1] = fmaxf(s[1] * dvv + b0.y, 0.f) + x0.y;
        o[2] = fmaxf(s[2] * dvv + b0.z, 0.f) + x0.z;
        o[3] = fmaxf(s[3] * dvv + b0.w, 0.f) + x0.w;
        o[4] = fmaxf(s[4] * dvv + b1.x, 0.f) + x1.x;
        o[5] = fmaxf(s[5] * dvv + b1.y, 0.f) + x1.y;
        o[6] = fmaxf(s[6] * dvv + b1.z, 0.f) + x1.z;
        o[7] = fmaxf(s[7] * dvv + b1.w, 0.f) + x1.w;
        short8 pk;
#pragma unroll
        for (int q = 0; q < 8; ++q) pk[q] = (short)f2b(o[q]);
        *reinterpret_cast<short8*>(h0 + (size_t)node * CIN + c16 * 8) = pk;
    }
}

// ---------------- out init (harness poisons d_out every call) ----------------

__global__ void init_out_k(float* __restrict__ out, const float* __restrict__ b3) {
    int i = blockIdx.x * 256 + threadIdx.x;
    if (i < NGRAPH) out[i] = b3[0];
}

// ---------------- fused MLP: gemm1 -> LDS -> gemm2 -> w3-dot -> atomicAdd ----
// Per block: 64 rows. Wave w computes cols [w*64, w*64+64) of both h1 and h2.
// h1 tile lives in LDS (bf16, stride 264 for alignment + even bank spread).
// out[row/20] += sum_col relu(h2[row][col]+b2[col]) * w3[col]

__global__ __launch_bounds__(256) void mlp_k(
    const unsigned short* __restrict__ h0, const unsigned short* __restrict__ w1,
    const float* __restrict__ b1, const unsigned short* __restrict__ w2,
    const float* __restrict__ b2, const float* __restrict__ w3,
    float* __restrict__ out)
{
    __shared__ unsigned short h1s[64][264];
    const int tid = threadIdx.x;
    const int w64 = (tid >> 6) * 64;
    const int lane = tid & 63;
    const int quad = lane >> 4;
    const int l16 = lane & 15;
    const int bm = blockIdx.x * 64;

    const short8 zed = {0, 0, 0, 0, 0, 0, 0, 0};
    f32x4 acc[4][4];
#pragma unroll
    for (int i = 0; i < 4; ++i)
#pragma unroll
        for (int j = 0; j < 4; ++j) {
            f32x4 z = {0.f, 0.f, 0.f, 0.f};
            acc[i][j] = z;
        }

    // ---- phase 1: h1 = relu(h0 @ W1^T + b1), K=128 ----
#pragma unroll
    for (int kt = 0; kt < 4; ++kt) {
        const int ka = kt * 32 + quad * 8;
        short8 a[4], b[4];
#pragma unroll
        for (int t = 0; t < 4; ++t) {
            int m = bm + t * 16 + l16;
            a[t] = (m < NNODES) ? *reinterpret_cast<const short8*>(h0 + (size_t)m * 128 + ka) : zed;
            int n = w64 + t * 16 + l16;
            b[t] = *reinterpret_cast<const short8*>(w1 + (size_t)n * 128 + ka);
        }
#pragma unroll
        for (int i = 0; i < 4; ++i)
#pragma unroll
            for (int j = 0; j < 4; ++j)
                acc[i][j] = __builtin_amdgcn_mfma_f32_16x16x32_bf16(a[i], b[j], acc[i][j], 0, 0, 0);
    }

#pragma unroll
    for (int nt = 0; nt < 4; ++nt) {
        int ncol = w64 + nt * 16 + l16;
        float bv = b1[ncol];
#pragma unroll
        for (int mt = 0; mt < 4; ++mt)
#pragma unroll
            for (int r = 0; r < 4; ++r) {
                int row = mt * 16 + quad * 4 + r;
                h1s[row][ncol] = f2b(fmaxf(acc[mt][nt][r] + bv, 0.f));
            }
    }
    __syncthreads();

    // ---- phase 2: h2 = relu(h1s @ W2^T + b2), K=256 ----
#pragma unroll
    for (int i = 0; i < 4; ++i)
#pragma unroll
        for (int j = 0; j < 4; ++j) {
            f32x4 z = {0.f, 0.f, 0.f, 0.f};
            acc[i][j] = z;
        }
#pragma unroll
    for (int kt = 0; kt < 8; ++kt) {
        const int ka = kt * 32 + quad * 8;
        short8 a[4], b[4];
#pragma unroll
        for (int t = 0; t < 4; ++t) {
            a[t] = *reinterpret_cast<const short8*>(&h1s[t * 16 + l16][ka]);
            int n = w64 + t * 16 + l16;
            b[t] = *reinterpret_cast<const short8*>(w2 + (size_t)n * 256 + ka);
        }
#pragma unroll
        for (int i = 0; i < 4; ++i)
#pragma unroll
            for (int j = 0; j < 4; ++j)
                acc[i][j] = __builtin_amdgcn_mfma_f32_16x16x32_bf16(a[i], b[j], acc[i][j], 0, 0, 0);
    }

    // ---- fused epilogue: part[mt][r] = sum over this wave's 64 cols ----
    float part[4][4];
#pragma unroll
    for (int mt = 0; mt < 4; ++mt)
#pragma unroll
        for (int r = 0; r < 4; ++r) part[mt][r] = 0.f;
#pragma unroll
    for (int nt = 0; nt < 4; ++nt) {
        int ncol = w64 + nt * 16 + l16;
        float bs = b2[ncol];
        float wv = w3[ncol];
#pragma unroll
        for (int mt = 0; mt < 4; ++mt)
#pragma unroll
            for (int r = 0; r < 4; ++r)
                part[mt][r] += fmaxf(acc[mt][nt][r] + bs, 0.f) * wv;
    }
    // reduce across the 16 col-lanes (bits 0..3 of lane)
#pragma unroll
    for (int mt = 0; mt < 4; ++mt)
#pragma unroll
        for (int r = 0; r < 4; ++r) {
            float v = part[mt][r];
            v += __shfl_xor(v, 1, 64);
            v += __shfl_xor(v, 2, 64);
            v += __shfl_xor(v, 4, 64);
            v += __shfl_xor(v, 8, 64);
            part[mt][r] = v;
        }
    if (l16 == 0) {
#pragma unroll
        for (int mt = 0; mt < 4; ++mt)
#pragma unroll
            for (int r = 0; r < 4; ++r) {
                int row = bm + mt * 16 + quad * 4 + r;
                if (row < NNODES) atomicAdd(&out[row / ACT], part[mt][r]);
            }
    }
}

// ---------------- launch ----------------

extern "C" void kernel_launch(void* const* d_in, const int* in_sizes, int n_in,
                              void* d_out, int out_size, void* d_ws, size_t ws_size,
                              hipStream_t stream)
{
    const float* x      = (const float*)d_in[0];
    const int*   ei     = (const int*)  d_in[1];
    const float* conv_w = (const float*)d_in[2];
    const float* conv_b = (const float*)d_in[3];
    const float* lin1_w = (const float*)d_in[4];
    const float* lin1_b = (const float*)d_in[5];
    const float* lin2_w = (const float*)d_in[6];
    const float* lin2_b = (const float*)d_in[7];
    const float* lin3_w = (const float*)d_in[8];
    const float* lin3_b = (const float*)d_in[9];
    float* out = (float*)d_out;

    // Workspace (~78 MB):
    //   xws bf16 [N*128] 25.6 MB | h0 bf16 [N*128] 25.6 MB
    //   entries u32 [NB*CAP] 12.8 MB | csr int [NB*CAP] 12.8 MB
    //   rowptr2 int2 [N] 800 KB | dinv [N] 400 KB | bfill [NB]
    //   wt0/wt1/wt2 bf16 weights ~229 KB
    unsigned short* xws     = (unsigned short*)d_ws;
    unsigned short* h0      = xws + (size_t)12800000;
    unsigned*       entries = (unsigned*)(h0 + (size_t)12800000);
    int*            csr     = (int*)(entries + (size_t)NB * CAP);
    int2*           rowptr2 = (int2*)(csr + (size_t)NB * CAP);
    float*          dinv    = (float*)(rowptr2 + NNODES);
    int*            bfill   = (int*)(dinv + NNODES);
    unsigned short* wt0     = (unsigned short*)(bfill + NB + 8);
    unsigned short* wt1     = wt0 + 16384;
    unsigned short* wt2     = wt1 + 32768;

    // CSR build (fixed-capacity bucket windows)
    hipMemsetAsync(bfill, 0, NB * sizeof(int), stream);
    bin_k<<<BIN_WGS, 256, 0, stream>>>(ei, bfill, entries);
    bucket_build_k<<<NB, 256, 0, stream>>>(entries, bfill, rowptr2, csr, dinv);

    // weight conversions (one launch)
    cvt_w_k<<<(114688 + 255) / 256, 256, 0, stream>>>(conv_w, lin1_w, lin2_w, wt0, wt1, wt2);

    // gemm0: xws = (x @ conv_w) * dinv[row]
    mgemm0_k<<<(NNODES + 127) / 128, 256, 0, stream>>>(x, wt0, dinv, xws, NNODES);

    // gather + conv epilogue -> h0 bf16
    gather_k<<<(NNODES + 3) / 4, 256, 0, stream>>>(rowptr2, csr, xws, dinv, x, conv_b, h0);

    // out = b3, then fused MLP accumulates into it
    init_out_k<<<(NGRAPH + 255) / 256, 256, 0, stream>>>(out, lin3_b);

    mlp_k<<<(NNODES + 63) / 64, 256, 0, stream>>>(h0, wt1, lin1_b, wt2, lin2_b, lin3_w, out);
}